// Round 1
// baseline (1766.392 us; speedup 1.0000x reference)
//
#include <hip/hip_runtime.h>

typedef unsigned short u16;
typedef __attribute__((ext_vector_type(8))) short short8;
typedef __attribute__((ext_vector_type(4))) float f32x4;

#define NLAYER 6
#define NH 16
#define DMODEL 1024
#define DHEAD 64
#define NVOCAB 32000
#define NB 2
#define NS 1024
#define NDFF 4096
#define MTOK (NB*NS)   // 2048

__device__ __forceinline__ u16 f2b(float f) {
    union { float f; unsigned u; } x; x.f = f;
    unsigned r = x.u + 0x7fffu + ((x.u >> 16) & 1u);
    return (u16)(r >> 16);
}

#define GLL16(gp, lp) __builtin_amdgcn_global_load_lds( \
    (const __attribute__((address_space(1))) void*)(gp), \
    (__attribute__((address_space(3))) void*)(lp), 16, 0, 0)

// ---------------------------------------------------------------------------
// Tiled transpose + f32->bf16 convert:  src [z][R][C] f32  ->  dst [z][C][R] bf16
// grid (C/32, R/32, nbatch), block (32,8)
__global__ void transpose_cvt(const float* __restrict__ src, u16* __restrict__ dst,
                              int R, int C, long srcStride, long dstStride)
{
    __shared__ float t[32][33];
    const int c0 = blockIdx.x * 32, r0 = blockIdx.y * 32;
    const float* s = src + (long)blockIdx.z * srcStride;
    u16* d = dst + (long)blockIdx.z * dstStride;
    const int tx = threadIdx.x, ty = threadIdx.y;
    #pragma unroll
    for (int j = 0; j < 32; j += 8)
        t[ty + j][tx] = s[(long)(r0 + ty + j) * C + c0 + tx];
    __syncthreads();
    #pragma unroll
    for (int j = 0; j < 32; j += 8)
        d[(long)(c0 + ty + j) * R + r0 + tx] = f2b(t[tx][ty + j]);
}

// Wq/Wk/Wv: src [NL,H,1024,64] -> dst [NL,3072,1024], section sel (0=q,1=k,2=v),
// head h occupies rows sel*1024 + h*64 .. +64. grid (2, 32, 96), block (32,8)
__global__ void transpose_qkv(const float* __restrict__ src, u16* __restrict__ dst, int sel)
{
    __shared__ float t[32][33];
    const int bi = blockIdx.z, l = bi >> 4, h = bi & 15;
    const float* s = src + (long)bi * (DMODEL * DHEAD);
    u16* d = dst + (long)l * 3072 * DMODEL + (long)(sel * 1024 + h * 64) * DMODEL;
    const int c0 = blockIdx.x * 32, r0 = blockIdx.y * 32;
    const int tx = threadIdx.x, ty = threadIdx.y;
    #pragma unroll
    for (int j = 0; j < 32; j += 8)
        t[ty + j][tx] = s[(long)(r0 + ty + j) * DHEAD + c0 + tx];
    __syncthreads();
    #pragma unroll
    for (int j = 0; j < 32; j += 8)
        d[(long)(c0 + ty + j) * DMODEL + r0 + tx] = f2b(t[tx][ty + j]);
}

// ---------------------------------------------------------------------------
// Embedding gather + positional encoding (base 1000, sin@even, cos@odd)
__global__ void embed_pe(const int* __restrict__ toks, const float* __restrict__ emb,
                         float* __restrict__ x, u16* __restrict__ xb)
{
    const int row = blockIdx.x;            // b*S + s
    const int s = row & (NS - 1);
    const long erow = (long)toks[row] * DMODEL;
    const long base = (long)row * DMODEL;
    #pragma unroll
    for (int j = 0; j < 4; ++j) {
        int d = threadIdx.x + j * 256;
        // angle = s / 1000^(d/1024) = s * 2^(-d/1024 * log2(1000))
        float ang = (float)s * exp2f(-(float)d * (9.965784284662087f / 1024.f));
        float pe = (d & 1) ? cosf(ang) : sinf(ang);
        float v = emb[erow + d] + pe;
        x[base + d] = v;
        xb[base + d] = f2b(v);
    }
}

// ---------------------------------------------------------------------------
// Residual add + LayerNorm; writes f32 residual stream and bf16 GEMM input
__global__ __launch_bounds__(256) void ln_residual(
    const float* __restrict__ xin, const float* __restrict__ delta,
    const float* __restrict__ g, const float* __restrict__ bb,
    float* __restrict__ xout, u16* __restrict__ xbout)
{
    __shared__ float red[8];
    const long base = (long)blockIdx.x * DMODEL;
    float v[4]; float sum = 0.f, sq = 0.f;
    #pragma unroll
    for (int j = 0; j < 4; ++j) {
        int d = threadIdx.x + j * 256;
        float t = xin[base + d] + delta[base + d];
        v[j] = t; sum += t; sq += t * t;
    }
    #pragma unroll
    for (int off = 1; off < 64; off <<= 1) {
        sum += __shfl_xor(sum, off, 64);
        sq  += __shfl_xor(sq,  off, 64);
    }
    const int wv = threadIdx.x >> 6, lane = threadIdx.x & 63;
    if (lane == 0) { red[wv] = sum; red[4 + wv] = sq; }
    __syncthreads();
    float ts = red[0] + red[1] + red[2] + red[3];
    float tq = red[4] + red[5] + red[6] + red[7];
    float mu = ts * (1.f / DMODEL);
    float var = tq * (1.f / DMODEL) - mu * mu;
    float rstd = rsqrtf(var + 1e-5f);
    #pragma unroll
    for (int j = 0; j < 4; ++j) {
        int d = threadIdx.x + j * 256;
        float y = (v[j] - mu) * rstd * g[d] + bb[d];
        xout[base + d] = y;
        xbout[base + d] = f2b(y);
    }
}

// ---------------------------------------------------------------------------
// GEMM: C[M,N] = A[M,K] @ Bt[N,K]^T, bf16 in, f32 acc. 128x128 tile, BK=32,
// 4 waves. EPI: 0=f32, 1=bf16, 2=relu->bf16, 3=f32+bias
template<int EPI>
__global__ __launch_bounds__(256, 2) void gemm_bt(
    const u16* __restrict__ A, const u16* __restrict__ Bt, void* __restrict__ Cout,
    const float* __restrict__ bias, int M, int N, int K)
{
    __shared__ __align__(16) u16 As[128 * 32];
    __shared__ __align__(16) u16 Bs[128 * 32];
    const int m0 = blockIdx.y * 128, n0 = blockIdx.x * 128;
    const int tid = threadIdx.x, wv = tid >> 6, lane = tid & 63;
    const int wr = wv >> 1, wc = wv & 1;
    const int lrow = lane & 15, lk8 = (lane >> 4) * 8;

    f32x4 acc[4][4] = {};

    for (int kt = 0; kt < K; kt += 32) {
        __syncthreads();
        #pragma unroll
        for (int i = 0; i < 2; ++i) {
            int c0 = (wv * 2 + i) * 64;
            int c = c0 + lane;
            int row = c >> 2, col = (c & 3) * 8;
            GLL16(A + (long)(m0 + row) * K + kt + col, As + c0 * 8);
        }
        #pragma unroll
        for (int i = 0; i < 2; ++i) {
            int c0 = (wv * 2 + i) * 64;
            int c = c0 + lane;
            int row = c >> 2, col = (c & 3) * 8;
            GLL16(Bt + (long)(n0 + row) * K + kt + col, Bs + c0 * 8);
        }
        __syncthreads();
        short8 a[4], b[4];
        #pragma unroll
        for (int m = 0; m < 4; ++m)
            a[m] = *(const short8*)(As + (wr * 64 + m * 16 + lrow) * 32 + lk8);
        #pragma unroll
        for (int n = 0; n < 4; ++n)
            b[n] = *(const short8*)(Bs + (wc * 64 + n * 16 + lrow) * 32 + lk8);
        #pragma unroll
        for (int m = 0; m < 4; ++m)
            #pragma unroll
            for (int n = 0; n < 4; ++n)
                acc[m][n] = __builtin_amdgcn_mfma_f32_16x16x32_bf16(a[m], b[n], acc[m][n], 0, 0, 0);
    }

    #pragma unroll
    for (int m = 0; m < 4; ++m) {
        const int r = m0 + wr * 64 + m * 16 + ((lane >> 4) << 2);
        #pragma unroll
        for (int n = 0; n < 4; ++n) {
            const int cidx = n0 + wc * 64 + n * 16 + lrow;
            if (EPI == 0) {
                float* C = (float*)Cout;
                #pragma unroll
                for (int i = 0; i < 4; ++i) C[(long)(r + i) * N + cidx] = acc[m][n][i];
            } else if (EPI == 3) {
                float* C = (float*)Cout;
                const float bv = bias[cidx];
                #pragma unroll
                for (int i = 0; i < 4; ++i) C[(long)(r + i) * N + cidx] = acc[m][n][i] + bv;
            } else {
                u16* C = (u16*)Cout;
                #pragma unroll
                for (int i = 0; i < 4; ++i) {
                    float vv = acc[m][n][i];
                    if (EPI == 2) vv = fmaxf(vv, 0.f);
                    C[(long)(r + i) * N + cidx] = f2b(vv);
                }
            }
        }
    }
}

// ---------------------------------------------------------------------------
// Flash attention: one block per (qt, h, b); 4 waves, each owns 16 q rows.
// qkv: bf16 [2048][3072] (q cols 0..1023 = h*64+dk, k +1024, v +2048)
// delta: f32 [2048][1024] output (attn, layout b,q,h*64+dk)
__global__ __launch_bounds__(256, 2) void attn_flash(
    const u16* __restrict__ qkv, float* __restrict__ delta)
{
    __shared__ __align__(16) u16 Qs[64 * 64];
    __shared__ __align__(16) u16 Ks[64 * 64];
    __shared__ __align__(16) u16 Vts[64 * 64];
    __shared__ __align__(16) u16 Ps[4][16 * 64];

    const int qt = blockIdx.x, h = blockIdx.y, b = blockIdx.z;
    const int tid = threadIdx.x, wv = tid >> 6, lane = tid & 63;
    const int lrow = lane & 15, lk8 = (lane >> 4) * 8, li4 = (lane >> 4) * 4;
    const long base = (long)b * NS * 3072;

    // stage Q tile [64 rows][64 dims]
    #pragma unroll
    for (int i = 0; i < 2; ++i) {
        int c0 = (wv * 2 + i) * 64;
        int c = c0 + lane;
        int row = c >> 3, col = (c & 7) * 8;
        GLL16(qkv + base + (long)(qt * 64 + row) * 3072 + h * 64 + col, Qs + c0 * 8);
    }

    f32x4 o[4] = {};
    float m_[4], l_[4];
    #pragma unroll
    for (int i = 0; i < 4; ++i) { m_[i] = -__builtin_inff(); l_[i] = 0.f; }

    for (int t = 0; t <= qt; ++t) {
        __syncthreads();
        // stage K tile
        #pragma unroll
        for (int i = 0; i < 2; ++i) {
            int c0 = (wv * 2 + i) * 64;
            int c = c0 + lane;
            int row = c >> 3, col = (c & 7) * 8;
            GLL16(qkv + base + (long)(t * 64 + row) * 3072 + 1024 + h * 64 + col, Ks + c0 * 8);
        }
        // stage V transposed: Vts[dk][kv]
        #pragma unroll
        for (int i = 0; i < 2; ++i) {
            int c = tid + i * 256;
            int kv = c >> 3, d0 = (c & 7) * 8;
            short8 vv = *(const short8*)(qkv + base + (long)(t * 64 + kv) * 3072 + 2048 + h * 64 + d0);
            #pragma unroll
            for (int j = 0; j < 8; ++j) Vts[(d0 + j) * 64 + kv] = ((u16*)&vv)[j];
        }
        __syncthreads();

        // S = Q K^T  (16 q rows x 64 kv cols per wave)
        short8 aq[2];
        aq[0] = *(const short8*)(Qs + (wv * 16 + lrow) * 64 + lk8);
        aq[1] = *(const short8*)(Qs + (wv * 16 + lrow) * 64 + 32 + lk8);
        f32x4 sa[4];
        #pragma unroll
        for (int nb = 0; nb < 4; ++nb) {
            f32x4 z = {};
            #pragma unroll
            for (int kd = 0; kd < 2; ++kd) {
                short8 bk = *(const short8*)(Ks + (nb * 16 + lrow) * 64 + kd * 32 + lk8);
                z = __builtin_amdgcn_mfma_f32_16x16x32_bf16(aq[kd], bk, z, 0, 0, 0);
            }
            sa[nb] = z;
        }
        // scale + causal mask (only diagonal tile needs it)
        const int qrow0 = qt * 64 + wv * 16 + li4;
        #pragma unroll
        for (int nb = 0; nb < 4; ++nb)
            #pragma unroll
            for (int i = 0; i < 4; ++i) {
                float sc = sa[nb][i] * 0.125f;
                if (t == qt) {
                    int kvc = t * 64 + nb * 16 + lrow;
                    if (kvc > qrow0 + i) sc = -__builtin_inff();
                }
                sa[nb][i] = sc;
            }
        // online softmax
        float mt[4];
        #pragma unroll
        for (int i = 0; i < 4; ++i)
            mt[i] = fmaxf(fmaxf(sa[0][i], sa[1][i]), fmaxf(sa[2][i], sa[3][i]));
        #pragma unroll
        for (int off = 1; off < 16; off <<= 1)
            #pragma unroll
            for (int i = 0; i < 4; ++i) mt[i] = fmaxf(mt[i], __shfl_xor(mt[i], off, 64));
        float fac[4], rs[4];
        #pragma unroll
        for (int i = 0; i < 4; ++i) {
            float mn = fmaxf(m_[i], mt[i]);
            fac[i] = expf(m_[i] - mn);
            m_[i] = mn;
            rs[i] = 0.f;
        }
        #pragma unroll
        for (int nb = 0; nb < 4; ++nb)
            #pragma unroll
            for (int i = 0; i < 4; ++i) {
                float p = expf(sa[nb][i] - m_[i]);
                sa[nb][i] = p; rs[i] += p;
            }
        #pragma unroll
        for (int off = 1; off < 16; off <<= 1)
            #pragma unroll
            for (int i = 0; i < 4; ++i) rs[i] += __shfl_xor(rs[i], off, 64);
        #pragma unroll
        for (int i = 0; i < 4; ++i) l_[i] = l_[i] * fac[i] + rs[i];
        #pragma unroll
        for (int nd = 0; nd < 4; ++nd)
            #pragma unroll
            for (int i = 0; i < 4; ++i) o[nd][i] *= fac[i];

        // P -> bf16 in wave-private LDS, reload as A-operand
        u16* ps = &Ps[wv][0];
        #pragma unroll
        for (int nb = 0; nb < 4; ++nb)
            #pragma unroll
            for (int i = 0; i < 4; ++i)
                ps[(li4 + i) * 64 + nb * 16 + lrow] = f2b(sa[nb][i]);
        short8 pa[2];
        pa[0] = *(const short8*)(ps + lrow * 64 + lk8);
        pa[1] = *(const short8*)(ps + lrow * 64 + 32 + lk8);
        #pragma unroll
        for (int nd = 0; nd < 4; ++nd)
            #pragma unroll
            for (int kd = 0; kd < 2; ++kd) {
                short8 vb = *(const short8*)(Vts + (nd * 16 + lrow) * 64 + kd * 32 + lk8);
                o[nd] = __builtin_amdgcn_mfma_f32_16x16x32_bf16(pa[kd], vb, o[nd], 0, 0, 0);
            }
    }

    // write attention output (un-normalized accumulator / l)
    #pragma unroll
    for (int i = 0; i < 4; ++i) {
        const long row = (long)b * NS + qt * 64 + wv * 16 + li4 + i;
        const float inv = 1.f / l_[i];
        #pragma unroll
        for (int nd = 0; nd < 4; ++nd)
            delta[row * DMODEL + h * 64 + nd * 16 + lrow] = o[nd][i] * inv;
    }
}

// ---------------------------------------------------------------------------
extern "C" void kernel_launch(void* const* d_in, const int* in_sizes, int n_in,
                              void* d_out, int out_size, void* d_ws, size_t ws_size,
                              hipStream_t stream) {
    const int*   toks  = (const int*)d_in[0];
    const float* emb   = (const float*)d_in[1];
    const float* Wq    = (const float*)d_in[2];
    const float* Wk    = (const float*)d_in[3];
    const float* Wv    = (const float*)d_in[4];
    const float* W1    = (const float*)d_in[5];
    const float* W2    = (const float*)d_in[6];
    const float* ln1g  = (const float*)d_in[7];
    const float* ln1b  = (const float*)d_in[8];
    const float* ln2g  = (const float*)d_in[9];
    const float* ln2b  = (const float*)d_in[10];
    const float* Wout  = (const float*)d_in[11];
    const float* bout  = (const float*)d_in[12];

    char* p = (char*)d_ws;
    auto alloc = [&](size_t bytes) { void* r = (void*)p; p += (bytes + 255) & ~(size_t)255; return r; };
    u16*   Wqkv_t = (u16*)alloc((size_t)NLAYER * 3072 * 1024 * 2);
    u16*   W1t    = (u16*)alloc((size_t)NLAYER * 4096 * 1024 * 2);
    u16*   W2t    = (u16*)alloc((size_t)NLAYER * 1024 * 4096 * 2);
    u16*   Woutt  = (u16*)alloc((size_t)NVOCAB * 1024 * 2);
    float* x      = (float*)alloc((size_t)MTOK * 1024 * 4);
    u16*   xb     = (u16*)alloc((size_t)MTOK * 1024 * 2);
    u16*   qkv    = (u16*)alloc((size_t)MTOK * 3072 * 2);
    u16*   hbuf   = (u16*)alloc((size_t)MTOK * 4096 * 2);
    float* dbuf   = (float*)alloc((size_t)MTOK * 1024 * 4);

    dim3 tb(32, 8);
    transpose_qkv<<<dim3(2, 32, 96), tb, 0, stream>>>(Wq, Wqkv_t, 0);
    transpose_qkv<<<dim3(2, 32, 96), tb, 0, stream>>>(Wk, Wqkv_t, 1);
    transpose_qkv<<<dim3(2, 32, 96), tb, 0, stream>>>(Wv, Wqkv_t, 2);
    transpose_cvt<<<dim3(128, 32, 6), tb, 0, stream>>>(W1, W1t, 1024, 4096, 1024l * 4096, 4096l * 1024);
    transpose_cvt<<<dim3(32, 128, 6), tb, 0, stream>>>(W2, W2t, 4096, 1024, 4096l * 1024, 1024l * 4096);
    transpose_cvt<<<dim3(1000, 32, 1), tb, 0, stream>>>(Wout, Woutt, 1024, NVOCAB, 0, 0);

    embed_pe<<<MTOK, 256, 0, stream>>>(toks, emb, x, xb);

    for (int l = 0; l < NLAYER; ++l) {
        gemm_bt<1><<<dim3(24, 16), 256, 0, stream>>>(
            xb, Wqkv_t + (size_t)l * 3072 * 1024, qkv, nullptr, MTOK, 3072, 1024);
        attn_flash<<<dim3(16, NH, NB), 256, 0, stream>>>(qkv, dbuf);
        ln_residual<<<MTOK, 256, 0, stream>>>(x, dbuf, ln1g + l * 1024, ln1b + l * 1024, x, xb);
        gemm_bt<2><<<dim3(32, 16), 256, 0, stream>>>(
            xb, W1t + (size_t)l * 4096 * 1024, hbuf, nullptr, MTOK, 4096, 1024);
        gemm_bt<0><<<dim3(8, 16), 256, 0, stream>>>(
            hbuf, W2t + (size_t)l * 1024 * 4096, dbuf, nullptr, MTOK, 1024, 4096);
        ln_residual<<<MTOK, 256, 0, stream>>>(x, dbuf, ln2g + l * 1024, ln2b + l * 1024, x, xb);
    }

    gemm_bt<3><<<dim3(250, 16), 256, 0, stream>>>(
        xb, Woutt, (float*)d_out, bout, MTOK, NVOCAB, 1024);
}

// Round 2
// 1305.258 us; speedup vs baseline: 1.3533x; 1.3533x over previous
//
#include <hip/hip_runtime.h>

typedef unsigned short u16;
typedef __attribute__((ext_vector_type(8))) short short8;
typedef __attribute__((ext_vector_type(4))) float f32x4;

#define NLAYER 6
#define NH 16
#define DMODEL 1024
#define DHEAD 64
#define NVOCAB 32000
#define NB 2
#define NS 1024
#define NDFF 4096
#define MTOK (NB*NS)   // 2048

__device__ __forceinline__ u16 f2b(float f) {
    union { float f; unsigned u; } x; x.f = f;
    unsigned r = x.u + 0x7fffu + ((x.u >> 16) & 1u);
    return (u16)(r >> 16);
}

#define GLL16(gp, lp) __builtin_amdgcn_global_load_lds( \
    (const __attribute__((address_space(1))) void*)(gp), \
    (__attribute__((address_space(3))) void*)(lp), 16, 0, 0)

// ---------------------------------------------------------------------------
// Tiled transpose + f32->bf16 convert:  src [z][R][C] f32  ->  dst [z][C][R] bf16
__global__ void transpose_cvt(const float* __restrict__ src, u16* __restrict__ dst,
                              int R, int C, long srcStride, long dstStride)
{
    __shared__ float t[32][33];
    const int c0 = blockIdx.x * 32, r0 = blockIdx.y * 32;
    const float* s = src + (long)blockIdx.z * srcStride;
    u16* d = dst + (long)blockIdx.z * dstStride;
    const int tx = threadIdx.x, ty = threadIdx.y;
    #pragma unroll
    for (int j = 0; j < 32; j += 8)
        t[ty + j][tx] = s[(long)(r0 + ty + j) * C + c0 + tx];
    __syncthreads();
    #pragma unroll
    for (int j = 0; j < 32; j += 8)
        d[(long)(c0 + ty + j) * R + r0 + tx] = f2b(t[tx][ty + j]);
}

// Wq/Wk/Wv: src [NL,H,1024,64] -> dst [NL,3072,1024]
__global__ void transpose_qkv(const float* __restrict__ src, u16* __restrict__ dst, int sel)
{
    __shared__ float t[32][33];
    const int bi = blockIdx.z, l = bi >> 4, h = bi & 15;
    const float* s = src + (long)bi * (DMODEL * DHEAD);
    u16* d = dst + (long)l * 3072 * DMODEL + (long)(sel * 1024 + h * 64) * DMODEL;
    const int c0 = blockIdx.x * 32, r0 = blockIdx.y * 32;
    const int tx = threadIdx.x, ty = threadIdx.y;
    #pragma unroll
    for (int j = 0; j < 32; j += 8)
        t[ty + j][tx] = s[(long)(r0 + ty + j) * DHEAD + c0 + tx];
    __syncthreads();
    #pragma unroll
    for (int j = 0; j < 32; j += 8)
        d[(long)(c0 + ty + j) * DMODEL + r0 + tx] = f2b(t[tx][ty + j]);
}

// ---------------------------------------------------------------------------
__global__ void embed_pe(const int* __restrict__ toks, const float* __restrict__ emb,
                         float* __restrict__ x, u16* __restrict__ xb)
{
    const int row = blockIdx.x;
    const int s = row & (NS - 1);
    const long erow = (long)toks[row] * DMODEL;
    const long base = (long)row * DMODEL;
    #pragma unroll
    for (int j = 0; j < 4; ++j) {
        int d = threadIdx.x + j * 256;
        float ang = (float)s * exp2f(-(float)d * (9.965784284662087f / 1024.f));
        float pe = (d & 1) ? cosf(ang) : sinf(ang);
        float v = emb[erow + d] + pe;
        x[base + d] = v;
        xb[base + d] = f2b(v);
    }
}

// ---------------------------------------------------------------------------
// Residual add + LayerNorm (ND deltas); writes f32 residual and bf16 GEMM input
template<int ND>
__global__ __launch_bounds__(256) void ln_residual(
    const float* __restrict__ xin, const float* __restrict__ delta,
    const float* __restrict__ delta2,
    const float* __restrict__ g, const float* __restrict__ bb,
    float* __restrict__ xout, u16* __restrict__ xbout)
{
    __shared__ float red[8];
    const long base = (long)blockIdx.x * DMODEL;
    float v[4]; float sum = 0.f, sq = 0.f;
    #pragma unroll
    for (int j = 0; j < 4; ++j) {
        int d = threadIdx.x + j * 256;
        float t = xin[base + d] + delta[base + d];
        if (ND == 2) t += delta2[base + d];
        v[j] = t; sum += t; sq += t * t;
    }
    #pragma unroll
    for (int off = 1; off < 64; off <<= 1) {
        sum += __shfl_xor(sum, off, 64);
        sq  += __shfl_xor(sq,  off, 64);
    }
    const int wv = threadIdx.x >> 6, lane = threadIdx.x & 63;
    if (lane == 0) { red[wv] = sum; red[4 + wv] = sq; }
    __syncthreads();
    float ts = red[0] + red[1] + red[2] + red[3];
    float tq = red[4] + red[5] + red[6] + red[7];
    float mu = ts * (1.f / DMODEL);
    float var = tq * (1.f / DMODEL) - mu * mu;
    float rstd = rsqrtf(var + 1e-5f);
    #pragma unroll
    for (int j = 0; j < 4; ++j) {
        int d = threadIdx.x + j * 256;
        float y = (v[j] - mu) * rstd * g[d] + bb[d];
        xout[base + d] = y;
        xbout[base + d] = f2b(y);
    }
}

// ---------------------------------------------------------------------------
// Pipelined GEMM: C[M,N] = A[M,K] @ Bt[N,K]^T, bf16 in, f32 acc.
// BM x BM tile, BK=32, 4 LDS buffers, counted vmcnt(8), 1 barrier/tile,
// XOR-swizzled LDS (both-sides), XCD-chunked block swizzle (rows inner).
// EPI: 0=f32 (+blockIdx.y*zstride), 1=bf16, 2=relu->bf16, 3=f32+bias
template<int BM, int EPI>
__global__ __launch_bounds__(BM*2, 2) void gemm_pipe(
    const u16* __restrict__ A, const u16* __restrict__ Bt,
    void* __restrict__ Cout, const float* __restrict__ bias,
    int M, int N, int K, int lda, int ldb, size_t zstride)
{
    constexpr int WAVES = BM / 32;          // 4 or 8
    constexpr int WC = WAVES / 2;           // wave cols: 2 or 4
    constexpr int MR = BM / 32;             // m-frags per wave: 4 or 8
    constexpr int TILE = BM * 32;           // elems per matrix per buffer

    __shared__ __align__(16) u16 As[4][TILE];
    __shared__ __align__(16) u16 Bs[4][TILE];

    const int nmb = M / BM;
    {   // nothing
    }
    const int id = blockIdx.x, nwg = gridDim.x;
    const int q = nwg >> 3, r = nwg & 7, xcd = id & 7, loc = id >> 3;
    const int swz = (xcd < r ? xcd * (q + 1) : r * (q + 1) + (xcd - r) * q) + loc;
    const int m0 = (swz % nmb) * BM, n0 = (swz / nmb) * BM;
    const int koff = blockIdx.y * K;

    const int tid = threadIdx.x, wv = tid >> 6, lane = tid & 63;
    const int wr = wv / WC, wc = wv % WC;
    const int lrow = lane & 15, ks = lane >> 4;

    // staging: 4 gll issues per wave per tile (A chunk0/1, B chunk0/1)
    const u16* gsrc[4];
    int ldso[2];
    {
        const int l4 = lane >> 2, s = lane & 3;
        #pragma unroll
        for (int j = 0; j < 2; ++j) {
            const int row = j * (WAVES * 16) + wv * 16 + l4;   // local tile row
            const int x = (row >> 1) & 3;                      // swizzle bits
            gsrc[j]     = A  + (size_t)(m0 + row) * lda + koff + (size_t)((s ^ x) * 8);
            gsrc[2 + j] = Bt + (size_t)(n0 + row) * ldb + koff + (size_t)((s ^ x) * 8);
            ldso[j] = (j * (WAVES * 16) + wv * 16) * 32;
        }
    }
    // fragment read offsets (swizzled)
    int aoff[MR], boff[4];
    #pragma unroll
    for (int m = 0; m < MR; ++m) {
        const int row = wr * (BM / 2) + m * 16 + lrow;
        aoff[m] = row * 32 + ((ks ^ ((row >> 1) & 3)) * 8);
    }
    #pragma unroll
    for (int n = 0; n < 4; ++n) {
        const int row = wc * 64 + n * 16 + lrow;
        boff[n] = row * 32 + ((ks ^ ((row >> 1) & 3)) * 8);
    }

    const int NT = K / 32;
    auto ISSUE = [&](int t) {
        const int b = t & 3;
        const size_t ko = (size_t)t * 32;
        #pragma unroll
        for (int j = 0; j < 2; ++j) {
            GLL16(gsrc[j] + ko,     &As[b][ldso[j]]);
            GLL16(gsrc[2 + j] + ko, &Bs[b][ldso[j]]);
        }
    };

    f32x4 acc[MR][4] = {};
    ISSUE(0); ISSUE(1); ISSUE(2);

    for (int t = 0; t < NT; ++t) {
        if (t < NT - 2)       { asm volatile("s_waitcnt vmcnt(8)" ::: "memory"); }
        else if (t == NT - 2) { asm volatile("s_waitcnt vmcnt(4)" ::: "memory"); }
        else                  { asm volatile("s_waitcnt vmcnt(0)" ::: "memory"); }
        __builtin_amdgcn_sched_barrier(0);
        __builtin_amdgcn_s_barrier();
        __builtin_amdgcn_sched_barrier(0);

        const int b = t & 3;
        short8 af[MR], bf[4];
        #pragma unroll
        for (int m = 0; m < MR; ++m) af[m] = *(const short8*)(&As[b][aoff[m]]);
        #pragma unroll
        for (int n = 0; n < 4; ++n)  bf[n] = *(const short8*)(&Bs[b][boff[n]]);
        if (t + 3 < NT) ISSUE(t + 3);
        __builtin_amdgcn_s_setprio(1);
        #pragma unroll
        for (int m = 0; m < MR; ++m)
            #pragma unroll
            for (int n = 0; n < 4; ++n)
                acc[m][n] = __builtin_amdgcn_mfma_f32_16x16x32_bf16(af[m], bf[n], acc[m][n], 0, 0, 0);
        __builtin_amdgcn_s_setprio(0);
    }

    // epilogue
    #pragma unroll
    for (int m = 0; m < MR; ++m) {
        const int rr = m0 + wr * (BM / 2) + m * 16 + ks * 4;
        #pragma unroll
        for (int n = 0; n < 4; ++n) {
            const int cc = n0 + wc * 64 + n * 16 + lrow;
            if (EPI == 0) {
                float* C = (float*)Cout + (size_t)blockIdx.y * zstride;
                #pragma unroll
                for (int i = 0; i < 4; ++i) C[(size_t)(rr + i) * N + cc] = acc[m][n][i];
            } else if (EPI == 3) {
                float* C = (float*)Cout;
                const float bv = bias[cc];
                #pragma unroll
                for (int i = 0; i < 4; ++i) C[(size_t)(rr + i) * N + cc] = acc[m][n][i] + bv;
            } else {
                u16* C = (u16*)Cout;
                #pragma unroll
                for (int i = 0; i < 4; ++i) {
                    float vv = acc[m][n][i];
                    if (EPI == 2) vv = fmaxf(vv, 0.f);
                    C[(size_t)(rr + i) * N + cc] = f2b(vv);
                }
            }
        }
    }
}

// ---------------------------------------------------------------------------
// Flash attention, load-balanced: block p handles q-tiles {p, 15-p}.
__global__ __launch_bounds__(256, 2) void attn_flash(
    const u16* __restrict__ qkv, float* __restrict__ delta)
{
    __shared__ __align__(16) u16 Qs[64 * 64];
    __shared__ __align__(16) u16 Ks[64 * 64];
    __shared__ __align__(16) u16 Vts[64 * 64];
    __shared__ __align__(16) u16 Ps[4][16 * 64];

    const int pair = blockIdx.x, h = blockIdx.y, b = blockIdx.z;
    const int tid = threadIdx.x, wv = tid >> 6, lane = tid & 63;
    const int lrow = lane & 15, lk8 = (lane >> 4) * 8, li4 = (lane >> 4) * 4;
    const long base = (long)b * NS * 3072;

    for (int rep = 0; rep < 2; ++rep) {
        const int qt = rep == 0 ? pair : 15 - pair;
        __syncthreads();   // protect Qs/Ks/Vts from previous rep's readers

        // stage Q tile [64 rows][64 dims]
        #pragma unroll
        for (int i = 0; i < 2; ++i) {
            int c0 = (wv * 2 + i) * 64;
            int c = c0 + lane;
            int row = c >> 3, col = (c & 7) * 8;
            GLL16(qkv + base + (long)(qt * 64 + row) * 3072 + h * 64 + col, Qs + c0 * 8);
        }

        f32x4 o[4] = {};
        float m_[4], l_[4];
        #pragma unroll
        for (int i = 0; i < 4; ++i) { m_[i] = -__builtin_inff(); l_[i] = 0.f; }

        for (int t = 0; t <= qt; ++t) {
            __syncthreads();
            #pragma unroll
            for (int i = 0; i < 2; ++i) {
                int c0 = (wv * 2 + i) * 64;
                int c = c0 + lane;
                int row = c >> 3, col = (c & 7) * 8;
                GLL16(qkv + base + (long)(t * 64 + row) * 3072 + 1024 + h * 64 + col, Ks + c0 * 8);
            }
            #pragma unroll
            for (int i = 0; i < 2; ++i) {
                int c = tid + i * 256;
                int kv = c >> 3, d0 = (c & 7) * 8;
                short8 vv = *(const short8*)(qkv + base + (long)(t * 64 + kv) * 3072 + 2048 + h * 64 + d0);
                #pragma unroll
                for (int j = 0; j < 8; ++j) Vts[(d0 + j) * 64 + kv] = ((u16*)&vv)[j];
            }
            __syncthreads();

            short8 aq[2];
            aq[0] = *(const short8*)(Qs + (wv * 16 + lrow) * 64 + lk8);
            aq[1] = *(const short8*)(Qs + (wv * 16 + lrow) * 64 + 32 + lk8);
            f32x4 sa[4];
            #pragma unroll
            for (int nb = 0; nb < 4; ++nb) {
                f32x4 z = {};
                #pragma unroll
                for (int kd = 0; kd < 2; ++kd) {
                    short8 bk = *(const short8*)(Ks + (nb * 16 + lrow) * 64 + kd * 32 + lk8);
                    z = __builtin_amdgcn_mfma_f32_16x16x32_bf16(aq[kd], bk, z, 0, 0, 0);
                }
                sa[nb] = z;
            }
            const int qrow0 = qt * 64 + wv * 16 + li4;
            #pragma unroll
            for (int nb = 0; nb < 4; ++nb)
                #pragma unroll
                for (int i = 0; i < 4; ++i) {
                    float sc = sa[nb][i] * 0.125f;
                    if (t == qt) {
                        int kvc = t * 64 + nb * 16 + lrow;
                        if (kvc > qrow0 + i) sc = -__builtin_inff();
                    }
                    sa[nb][i] = sc;
                }
            float mt[4];
            #pragma unroll
            for (int i = 0; i < 4; ++i)
                mt[i] = fmaxf(fmaxf(sa[0][i], sa[1][i]), fmaxf(sa[2][i], sa[3][i]));
            #pragma unroll
            for (int off = 1; off < 16; off <<= 1)
                #pragma unroll
                for (int i = 0; i < 4; ++i) mt[i] = fmaxf(mt[i], __shfl_xor(mt[i], off, 64));
            float fac[4], rs[4];
            #pragma unroll
            for (int i = 0; i < 4; ++i) {
                float mn = fmaxf(m_[i], mt[i]);
                fac[i] = expf(m_[i] - mn);
                m_[i] = mn;
                rs[i] = 0.f;
            }
            #pragma unroll
            for (int nb = 0; nb < 4; ++nb)
                #pragma unroll
                for (int i = 0; i < 4; ++i) {
                    float p = expf(sa[nb][i] - m_[i]);
                    sa[nb][i] = p; rs[i] += p;
                }
            #pragma unroll
            for (int off = 1; off < 16; off <<= 1)
                #pragma unroll
                for (int i = 0; i < 4; ++i) rs[i] += __shfl_xor(rs[i], off, 64);
            #pragma unroll
            for (int i = 0; i < 4; ++i) l_[i] = l_[i] * fac[i] + rs[i];
            #pragma unroll
            for (int nd = 0; nd < 4; ++nd)
                #pragma unroll
                for (int i = 0; i < 4; ++i) o[nd][i] *= fac[i];

            u16* ps = &Ps[wv][0];
            #pragma unroll
            for (int nb = 0; nb < 4; ++nb)
                #pragma unroll
                for (int i = 0; i < 4; ++i)
                    ps[(li4 + i) * 64 + nb * 16 + lrow] = f2b(sa[nb][i]);
            short8 pa[2];
            pa[0] = *(const short8*)(ps + lrow * 64 + lk8);
            pa[1] = *(const short8*)(ps + lrow * 64 + 32 + lk8);
            #pragma unroll
            for (int nd = 0; nd < 4; ++nd)
                #pragma unroll
                for (int kd = 0; kd < 2; ++kd) {
                    short8 vb = *(const short8*)(Vts + (nd * 16 + lrow) * 64 + kd * 32 + lk8);
                    o[nd] = __builtin_amdgcn_mfma_f32_16x16x32_bf16(pa[kd], vb, o[nd], 0, 0, 0);
                }
        }

        #pragma unroll
        for (int i = 0; i < 4; ++i) {
            const long row = (long)b * NS + qt * 64 + wv * 16 + li4 + i;
            const float inv = 1.f / l_[i];
            #pragma unroll
            for (int nd = 0; nd < 4; ++nd)
                delta[row * DMODEL + h * 64 + nd * 16 + lrow] = o[nd][i] * inv;
        }
    }
}

// ---------------------------------------------------------------------------
extern "C" void kernel_launch(void* const* d_in, const int* in_sizes, int n_in,
                              void* d_out, int out_size, void* d_ws, size_t ws_size,
                              hipStream_t stream) {
    const int*   toks  = (const int*)d_in[0];
    const float* emb   = (const float*)d_in[1];
    const float* Wq    = (const float*)d_in[2];
    const float* Wk    = (const float*)d_in[3];
    const float* Wv    = (const float*)d_in[4];
    const float* W1    = (const float*)d_in[5];
    const float* W2    = (const float*)d_in[6];
    const float* ln1g  = (const float*)d_in[7];
    const float* ln1b  = (const float*)d_in[8];
    const float* ln2g  = (const float*)d_in[9];
    const float* ln2b  = (const float*)d_in[10];
    const float* Wout  = (const float*)d_in[11];
    const float* bout  = (const float*)d_in[12];

    char* p = (char*)d_ws;
    auto alloc = [&](size_t bytes) { void* r = (void*)p; p += (bytes + 255) & ~(size_t)255; return r; };
    u16*   Wqkv_t = (u16*)alloc((size_t)NLAYER * 3072 * 1024 * 2);
    u16*   W1t    = (u16*)alloc((size_t)NLAYER * 4096 * 1024 * 2);
    u16*   W2t    = (u16*)alloc((size_t)NLAYER * 1024 * 4096 * 2);
    u16*   Woutt  = (u16*)alloc((size_t)NVOCAB * 1024 * 2);
    float* x      = (float*)alloc((size_t)MTOK * 1024 * 4);
    u16*   xb     = (u16*)alloc((size_t)MTOK * 1024 * 2);
    u16*   qkv    = (u16*)alloc((size_t)MTOK * 3072 * 2);
    u16*   hbuf   = (u16*)alloc((size_t)MTOK * 4096 * 2);
    float* dbuf   = (float*)alloc((size_t)MTOK * 1024 * 4);

    float* hbufF = (float*)hbuf;               // attn output (dead region then)
    float* part2 = (float*)qkv;                // FFN2 split-K partial 2 (qkv dead then)
    const size_t zstride = (size_t)(part2 - dbuf);   // element offset dbuf -> part2

    dim3 tb(32, 8);
    transpose_qkv<<<dim3(2, 32, 96), tb, 0, stream>>>(Wq, Wqkv_t, 0);
    transpose_qkv<<<dim3(2, 32, 96), tb, 0, stream>>>(Wk, Wqkv_t, 1);
    transpose_qkv<<<dim3(2, 32, 96), tb, 0, stream>>>(Wv, Wqkv_t, 2);
    transpose_cvt<<<dim3(128, 32, 6), tb, 0, stream>>>(W1, W1t, 1024, 4096, 1024l * 4096, 4096l * 1024);
    transpose_cvt<<<dim3(32, 128, 6), tb, 0, stream>>>(W2, W2t, 4096, 1024, 4096l * 1024, 1024l * 4096);
    transpose_cvt<<<dim3(1000, 32, 1), tb, 0, stream>>>(Wout, Woutt, 1024, NVOCAB, 0, 0);

    embed_pe<<<MTOK, 256, 0, stream>>>(toks, emb, x, xb);

    for (int l = 0; l < NLAYER; ++l) {
        gemm_pipe<128, 1><<<dim3(16 * 24), 256, 0, stream>>>(
            xb, Wqkv_t + (size_t)l * 3072 * 1024, qkv, nullptr, MTOK, 3072, 1024, 1024, 1024, 0);
        attn_flash<<<dim3(8, NH, NB), 256, 0, stream>>>(qkv, hbufF);
        ln_residual<1><<<MTOK, 256, 0, stream>>>(x, hbufF, nullptr,
            ln1g + l * 1024, ln1b + l * 1024, x, xb);
        gemm_pipe<128, 2><<<dim3(16 * 32), 256, 0, stream>>>(
            xb, W1t + (size_t)l * 4096 * 1024, hbuf, nullptr, MTOK, 4096, 1024, 1024, 1024, 0);
        gemm_pipe<128, 0><<<dim3(16 * 8, 2), 256, 0, stream>>>(
            hbuf, W2t + (size_t)l * 1024 * 4096, dbuf, nullptr, MTOK, 1024, 2048, 4096, 4096, zstride);
        ln_residual<2><<<MTOK, 256, 0, stream>>>(x, dbuf, part2,
            ln2g + l * 1024, ln2b + l * 1024, x, xb);
    }

    gemm_pipe<256, 3><<<dim3(8 * 125), 512, 0, stream>>>(
        xb, Woutt, (float*)d_out, bout, MTOK, NVOCAB, 1024, 1024, 1024, 0);
}